// Round 7
// baseline (135.046 us; speedup 1.0000x reference)
//
#include <hip/hip_runtime.h>
#include <math.h>

#define Bsz 2048
#define Lsz 1024
#define SW  8   // waves (batches) per scan block

// ws layout (float offsets)
#define OFF_G   0        // h table (prep1), then true Gram (prep2)  64x64
#define OFF_GC  4096     // c_v * G[v][:]      64x64
#define OFF_P   8192     // (legacy slot, unused by scan)
#define OFF_WC  12288    // read_w @ out_w     64x64
#define OFF_GV  16384    // g per token        64
#define OFF_C   16448    // c = g/dn per token 64
#define OFF_BC  16512    // read_b@out_w+out_b 64
#define OFF_PG  20480    // g_v * (h_v @ Wc)   65x64 (row 64 = zeros, dummy token)

__device__ __forceinline__ float __rlf(float v, int i) {
    return __int_as_float(__builtin_amdgcn_readlane(__float_as_int(v), i));
}

// ---------------- prep1: per-token h/g/c (blocks 0..63), Wc rows (64..127), bc (128)
__global__ __launch_bounds__(128) void prep1_kernel(
    const float* __restrict__ embed_W, const float* __restrict__ ff_w1, const float* __restrict__ ff_b1,
    const float* __restrict__ ff_w2, const float* __restrict__ ff_b2, const float* __restrict__ ln_g,
    const float* __restrict__ ln_b, const float* __restrict__ gate_w1, const float* __restrict__ gate_b1,
    const float* __restrict__ gate_w2, const float* __restrict__ gate_b2, const float* __restrict__ read_w,
    const float* __restrict__ read_b, const float* __restrict__ out_w, const float* __restrict__ out_b,
    float* __restrict__ ws)
{
    const int tid = threadIdx.x;
    const int blk = blockIdx.x;
    if (blk < 64) {
        const int v = blk;
        __shared__ float z[128];
        __shared__ float hsh[64];
        const float* Ev = embed_W + (v << 6);
        float a = ff_b1[tid];
        #pragma unroll
        for (int i = 0; i < 64; ++i) a = fmaf(Ev[i], ff_w1[i * 128 + tid], a);
        z[tid] = fmaxf(a, 0.0f);
        __syncthreads();
        if (tid < 64) {   // wave 0 only
            float x = Ev[tid] + ff_b2[tid];
            #pragma unroll
            for (int j = 0; j < 128; ++j) x = fmaf(z[j], ff_w2[j * 64 + tid], x);
            float mu = x;
            #pragma unroll
            for (int off = 32; off > 0; off >>= 1) mu += __shfl_xor(mu, off);
            mu *= (1.0f / 64.0f);
            const float dd = x - mu;
            float var = dd * dd;
            #pragma unroll
            for (int off = 32; off > 0; off >>= 1) var += __shfl_xor(var, off);
            var *= (1.0f / 64.0f);
            const float rstd = rsqrtf(var + 1e-5f);
            const float hv = fmaf(dd * rstd, ln_g[tid], ln_b[tid]);
            hsh[tid] = hv;
            float dn = hv * hv;
            #pragma unroll
            for (int off = 32; off > 0; off >>= 1) dn += __shfl_xor(dn, off);
            dn += 1e-6f;
            float a2 = 0.0f;
            if (tid < 16) {
                float um = gate_b1[tid];
                #pragma unroll
                for (int i = 0; i < 64; ++i) um = fmaf(hsh[i], gate_w1[i * 16 + tid], um);
                a2 = fmaxf(um, 0.0f) * gate_w2[tid];
            }
            #pragma unroll
            for (int off = 8; off > 0; off >>= 1) a2 += __shfl_xor(a2, off);
            // store h into the OFF_G region as a staging table; prep2 reads it
            // and overwrites it in place with the true Gram.
            ws[OFF_G + (v << 6) + tid] = hv;
            if (tid == 0) {
                a2 += gate_b2[0];
                const float g = 1.0f / (1.0f + expf(-a2));
                ws[OFF_GV + v] = g;
                ws[OFF_C + v]  = g / dn;
            }
        }
    } else if (blk < 128) {
        const int j = blk - 64;
        if (tid < 64) {
            float a = 0.0f;
            #pragma unroll
            for (int m = 0; m < 64; ++m) a = fmaf(read_w[(j << 6) + m], out_w[(m << 6) + tid], a);
            ws[OFF_WC + (j << 6) + tid] = a;
        }
    } else {
        if (tid < 64) {
            float a = out_b[tid];
            #pragma unroll
            for (int jj = 0; jj < 64; ++jj) a = fmaf(read_b[jj], out_w[(jj << 6) + tid], a);
            ws[OFF_BC + tid] = a;
        }
    }
}

// ---------------- prep2: Gram/Gc rows (blocks 0..63) — overwrites OFF_G in place
// with the true Gram; Pg rows (64..127) to OFF_PG with g pre-folded;
// block 128 zeroes the dummy-token row of Pg.
__global__ __launch_bounds__(64) void prep2_kernel(float* __restrict__ ws)
{
    const int tid = threadIdx.x;
    const int blk = blockIdx.x;
    if (blk == 128) {
        ws[OFF_PG + 4096 + tid] = 0.0f;   // dummy token 64 row of Pg
        return;
    }
    __shared__ float tT[65 * 64];   // tT[j*65+w] = h[w][j] (padded)
    for (int idx = tid; idx < 4096; idx += 64) {
        const int w = idx >> 6, j = idx & 63;
        tT[j * 65 + w] = ws[OFF_G + idx];   // h table
    }
    __syncthreads();
    if (blk < 64) {
        const int v = blk;
        const float cv = ws[OFF_C + v];
        float a = 0.0f;
        #pragma unroll
        for (int j = 0; j < 64; ++j) a = fmaf(tT[j * 65 + v], tT[j * 65 + tid], a);
        ws[OFF_G  + (v << 6) + tid] = a;      // true Gram row v (safe: LDS copy taken)
        ws[OFF_GC + (v << 6) + tid] = cv * a;
    } else {
        const int v = blk - 64;
        const float gv = ws[OFF_GV + v];
        float a = 0.0f;
        #pragma unroll
        for (int j = 0; j < 64; ++j)
            a = fmaf(tT[j * 65 + v], ws[OFF_WC + (j << 6) + tid], a);
        ws[OFF_PG + (v << 6) + tid] = gv * a;  // g folded into Pg
    }
}

// ---------------- scan: one wave per batch; packed tokens (4/int, scalar-pipe
// extraction), symmetric A/B 16-step pipeline. Per step the two gathers are
// SPLIT ACROSS PIPES: gc via ds_read_b32 (LDS), pg via global_load_dword
// (L1/L2-resident 16.5KB table) -> halves the LDS-issue cost per step.
//   d = readlane(D,tok); D = fma(-d, gc, D); acc = fma(d, pg, acc)
__global__ __launch_bounds__(SW * 64) void scan_kernel(const int* __restrict__ seq,
                                                       const float* __restrict__ ws,
                                                       float* __restrict__ out)
{
    __shared__ float ldsGc[65 * 64];          // rows 0..63 real; row 64 zeros (dummy tok 64)
    __shared__ int   pk[SW][16 + 256 + 64];   // packed tokens; P=pk+16; front pad=dummy
    __shared__ float ldsbc[64];

    const int tid  = threadIdx.x;
    const int wave = tid >> 6;
    const int lane = tid & 63;

    {
        const float4* srcGc = (const float4*)(ws + OFF_GC);
        float4* dGc = (float4*)ldsGc;
        for (int i = tid; i < 1024; i += SW * 64) dGc[i] = srcGc[i];
    }
    if (tid < 64) {
        ldsGc[4096 + tid] = 0.0f;
        ldsbc[tid] = ws[OFF_BC + tid];
    }
    const float* __restrict__ Pg = ws + OFF_PG;   // 65x64, row 64 zeros

    const int b = blockIdx.x * SW + wave;
    int* P = pk[wave] + 16;
    {
        const int4* src = (const int4*)(seq + (size_t)b * Lsz);
        #pragma unroll
        for (int i = 0; i < 4; ++i) {
            const int4 tv = src[i * 64 + lane];
            P[i * 64 + lane] = tv.x | (tv.y << 8) | (tv.z << 16) | (tv.w << 24);
        }
        if (lane < 16) pk[wave][lane] = 0x40404040;   // front pad: token 64 (dummy)
    }
    __syncthreads();

    // last word holds steps 1020..1023; step 1023 is the query -> replace with dummy 64
    const int lastw = P[255];
    const int tokL  = (lastw >> 24) & 0xFF;
    if (lane == 0) P[255] = (lastw & 0x00FFFFFF) | (64 << 24);

    float D   = ws[OFF_G + (tokL << 6) + lane];   // D_v = h_v . q  (true Gram, L2-hot)
    float acc = ldsbc[lane];                      // logits accumulator

    int   tkA[16], tkB[16];
    float gcA[16], gcB[16], pgA[16], pgB[16];

    // prologue: block 0 words (steps 1023..992); group 0 (A, lanes 7..4),
    // group 1 (B, lanes 3..0)
    int tokv = P[248 + lane];
    #pragma unroll
    for (int j = 0; j < 4; ++j) {
        const int w = __builtin_amdgcn_readlane(tokv, 7 - j);
        tkA[4 * j + 0] = (w >> 24) & 0xFF;
        tkA[4 * j + 1] = (w >> 16) & 0xFF;
        tkA[4 * j + 2] = (w >>  8) & 0xFF;
        tkA[4 * j + 3] =  w        & 0xFF;
    }
    #pragma unroll
    for (int k = 0; k < 16; ++k) {
        const int off = (tkA[k] << 6) + lane;
        gcA[k] = ldsGc[off];
        pgA[k] = Pg[off];
    }
    #pragma unroll
    for (int j = 0; j < 4; ++j) {
        const int w = __builtin_amdgcn_readlane(tokv, 3 - j);
        tkB[4 * j + 0] = (w >> 24) & 0xFF;
        tkB[4 * j + 1] = (w >> 16) & 0xFF;
        tkB[4 * j + 2] = (w >>  8) & 0xFF;
        tkB[4 * j + 3] =  w        & 0xFF;
    }
    #pragma unroll
    for (int k = 0; k < 16; ++k) {
        const int off = (tkB[k] << 6) + lane;
        gcB[k] = ldsGc[off];
        pgB[k] = Pg[off];
    }

    // iteration n computes groups 2n (A), 2n+1 (B); gathers 2n+2, 2n+3 from
    // block n+1 words. n=31 gathers from the front pad (dummy) harmlessly.
    for (int n = 0; n < 32; ++n) {
        const int tokvN = P[240 - 8 * n + lane];   // block n+1 (n=31 -> pad)
        // compute A: group 2n  (chain: readlane -> fma(D); acc chain independent)
        #pragma unroll
        for (int k = 0; k < 16; ++k) {
            const float d = __rlf(D, tkA[k]);
            D   = fmaf(-d, gcA[k], D);
            acc = fmaf( d, pgA[k], acc);
        }
        // refill A: group 2n+2 tokens (tokvN lanes 7..4) + gathers
        #pragma unroll
        for (int j = 0; j < 4; ++j) {
            const int w = __builtin_amdgcn_readlane(tokvN, 7 - j);
            tkA[4 * j + 0] = (w >> 24) & 0xFF;
            tkA[4 * j + 1] = (w >> 16) & 0xFF;
            tkA[4 * j + 2] = (w >>  8) & 0xFF;
            tkA[4 * j + 3] =  w        & 0xFF;
        }
        #pragma unroll
        for (int k = 0; k < 16; ++k) {
            const int off = (tkA[k] << 6) + lane;
            gcA[k] = ldsGc[off];
            pgA[k] = Pg[off];
        }
        // compute B: group 2n+1
        #pragma unroll
        for (int k = 0; k < 16; ++k) {
            const float d = __rlf(D, tkB[k]);
            D   = fmaf(-d, gcB[k], D);
            acc = fmaf( d, pgB[k], acc);
        }
        // refill B: group 2n+3 tokens (tokvN lanes 3..0) + gathers
        #pragma unroll
        for (int j = 0; j < 4; ++j) {
            const int w = __builtin_amdgcn_readlane(tokvN, 3 - j);
            tkB[4 * j + 0] = (w >> 24) & 0xFF;
            tkB[4 * j + 1] = (w >> 16) & 0xFF;
            tkB[4 * j + 2] = (w >>  8) & 0xFF;
            tkB[4 * j + 3] =  w        & 0xFF;
        }
        #pragma unroll
        for (int k = 0; k < 16; ++k) {
            const int off = (tkB[k] << 6) + lane;
            gcB[k] = ldsGc[off];
            pgB[k] = Pg[off];
        }
    }

    out[(size_t)b * 64 + lane] = acc;
}

extern "C" void kernel_launch(void* const* d_in, const int* in_sizes, int n_in,
                              void* d_out, int out_size, void* d_ws, size_t ws_size,
                              hipStream_t stream) {
    const int*   seq     = (const int*)  d_in[0];
    const float* embed_W = (const float*)d_in[1];
    const float* ff_w1   = (const float*)d_in[2];
    const float* ff_b1   = (const float*)d_in[3];
    const float* ff_w2   = (const float*)d_in[4];
    const float* ff_b2   = (const float*)d_in[5];
    const float* ln_g    = (const float*)d_in[6];
    const float* ln_b    = (const float*)d_in[7];
    const float* gate_w1 = (const float*)d_in[8];
    const float* gate_b1 = (const float*)d_in[9];
    const float* gate_w2 = (const float*)d_in[10];
    const float* gate_b2 = (const float*)d_in[11];
    const float* read_w  = (const float*)d_in[12];
    const float* read_b  = (const float*)d_in[13];
    const float* out_w   = (const float*)d_in[14];
    const float* out_b   = (const float*)d_in[15];
    float* ws  = (float*)d_ws;
    float* out = (float*)d_out;

    hipLaunchKernelGGL(prep1_kernel, dim3(129), dim3(128), 0, stream,
                       embed_W, ff_w1, ff_b1, ff_w2, ff_b2, ln_g, ln_b,
                       gate_w1, gate_b1, gate_w2, gate_b2, read_w, read_b,
                       out_w, out_b, ws);
    hipLaunchKernelGGL(prep2_kernel, dim3(129), dim3(64), 0, stream, ws);
    hipLaunchKernelGGL(scan_kernel, dim3(Bsz / SW), dim3(SW * 64), 0, stream,
                       seq, ws, out);
}

// Round 8
// 121.477 us; speedup vs baseline: 1.1117x; 1.1117x over previous
//
#include <hip/hip_runtime.h>
#include <math.h>

#define Bsz 2048
#define Lsz 1024
#define SW  8   // waves (batches) per scan block

// ws layout (float offsets)
#define OFF_G   0        // h table (prep1), then true Gram (prep2)  64x64
#define OFF_GC  4096     // c_v * G[v][:]      64x64
#define OFF_P   8192     // g_v * (h_v @ (read_w@out_w))  64x64  (g pre-folded)
#define OFF_WC  12288    // read_w @ out_w     64x64
#define OFF_GV  16384    // g per token        64
#define OFF_C   16448    // c = g/dn per token 64
#define OFF_BC  16512    // read_b@out_w+out_b 64

__device__ __forceinline__ float __rlf(float v, int i) {
    return __int_as_float(__builtin_amdgcn_readlane(__float_as_int(v), i));
}

// ---------------- prep1: per-token h/g/c (blocks 0..63), Wc rows (64..127), bc (128)
__global__ __launch_bounds__(128) void prep1_kernel(
    const float* __restrict__ embed_W, const float* __restrict__ ff_w1, const float* __restrict__ ff_b1,
    const float* __restrict__ ff_w2, const float* __restrict__ ff_b2, const float* __restrict__ ln_g,
    const float* __restrict__ ln_b, const float* __restrict__ gate_w1, const float* __restrict__ gate_b1,
    const float* __restrict__ gate_w2, const float* __restrict__ gate_b2, const float* __restrict__ read_w,
    const float* __restrict__ read_b, const float* __restrict__ out_w, const float* __restrict__ out_b,
    float* __restrict__ ws)
{
    const int tid = threadIdx.x;
    const int blk = blockIdx.x;
    if (blk < 64) {
        const int v = blk;
        __shared__ float z[128];
        __shared__ float hsh[64];
        const float* Ev = embed_W + (v << 6);
        float a = ff_b1[tid];
        #pragma unroll
        for (int i = 0; i < 64; ++i) a = fmaf(Ev[i], ff_w1[i * 128 + tid], a);
        z[tid] = fmaxf(a, 0.0f);
        __syncthreads();
        if (tid < 64) {   // wave 0 only
            float x = Ev[tid] + ff_b2[tid];
            #pragma unroll
            for (int j = 0; j < 128; ++j) x = fmaf(z[j], ff_w2[j * 64 + tid], x);
            float mu = x;
            #pragma unroll
            for (int off = 32; off > 0; off >>= 1) mu += __shfl_xor(mu, off);
            mu *= (1.0f / 64.0f);
            const float dd = x - mu;
            float var = dd * dd;
            #pragma unroll
            for (int off = 32; off > 0; off >>= 1) var += __shfl_xor(var, off);
            var *= (1.0f / 64.0f);
            const float rstd = rsqrtf(var + 1e-5f);
            const float hv = fmaf(dd * rstd, ln_g[tid], ln_b[tid]);
            hsh[tid] = hv;
            float dn = hv * hv;
            #pragma unroll
            for (int off = 32; off > 0; off >>= 1) dn += __shfl_xor(dn, off);
            dn += 1e-6f;
            float a2 = 0.0f;
            if (tid < 16) {
                float um = gate_b1[tid];
                #pragma unroll
                for (int i = 0; i < 64; ++i) um = fmaf(hsh[i], gate_w1[i * 16 + tid], um);
                a2 = fmaxf(um, 0.0f) * gate_w2[tid];
            }
            #pragma unroll
            for (int off = 8; off > 0; off >>= 1) a2 += __shfl_xor(a2, off);
            // store h into the OFF_G region as a staging table; prep2 reads it
            // and overwrites it in place with the true Gram.
            ws[OFF_G + (v << 6) + tid] = hv;
            if (tid == 0) {
                a2 += gate_b2[0];
                const float g = 1.0f / (1.0f + expf(-a2));
                ws[OFF_GV + v] = g;
                ws[OFF_C + v]  = g / dn;
            }
        }
    } else if (blk < 128) {
        const int j = blk - 64;
        if (tid < 64) {
            float a = 0.0f;
            #pragma unroll
            for (int m = 0; m < 64; ++m) a = fmaf(read_w[(j << 6) + m], out_w[(m << 6) + tid], a);
            ws[OFF_WC + (j << 6) + tid] = a;
        }
    } else {
        if (tid < 64) {
            float a = out_b[tid];
            #pragma unroll
            for (int jj = 0; jj < 64; ++jj) a = fmaf(read_b[jj], out_w[(jj << 6) + tid], a);
            ws[OFF_BC + tid] = a;
        }
    }
}

// ---------------- prep2: Gram/Gc rows (blocks 0..63) — overwrites OFF_G in place
// with the true Gram; P rows (64..127) with g pre-folded.
__global__ __launch_bounds__(64) void prep2_kernel(float* __restrict__ ws)
{
    const int tid = threadIdx.x;
    const int blk = blockIdx.x;
    __shared__ float tT[65 * 64];   // tT[j*65+w] = h[w][j] (padded)
    for (int idx = tid; idx < 4096; idx += 64) {
        const int w = idx >> 6, j = idx & 63;
        tT[j * 65 + w] = ws[OFF_G + idx];   // h table
    }
    __syncthreads();
    if (blk < 64) {
        const int v = blk;
        const float cv = ws[OFF_C + v];
        float a = 0.0f;
        #pragma unroll
        for (int j = 0; j < 64; ++j) a = fmaf(tT[j * 65 + v], tT[j * 65 + tid], a);
        ws[OFF_G  + (v << 6) + tid] = a;      // true Gram row v (safe: LDS copy taken)
        ws[OFF_GC + (v << 6) + tid] = cv * a;
    } else {
        const int v = blk - 64;
        const float gv = ws[OFF_GV + v];
        float a = 0.0f;
        #pragma unroll
        for (int j = 0; j < 64; ++j)
            a = fmaf(tT[j * 65 + v], ws[OFF_WC + (j << 6) + tid], a);
        ws[OFF_P + (v << 6) + tid] = gv * a;  // g folded into P
    }
}

// ---------------- scan: one wave per batch; packed tokens (4/int, scalar-pipe
// extraction), symmetric A/B 16-step pipeline, 1 ds_read_b64 per step fetching
// the interleaved (gc, pg) pair. Per step:
//   d = readlane(D,tok); D = fma(-d, gc, D); acc = fma(d, pg, acc)
// s_setprio(1) wraps the serial compute phases (T5: independent waves at
// different phases -> scheduler favors the latency-critical chain).
__global__ __launch_bounds__(SW * 64) void scan_kernel(const int* __restrict__ seq,
                                                       const float* __restrict__ ws,
                                                       float* __restrict__ out)
{
    __shared__ float2 ldsGP[65 * 64];         // rows 0..63: (gc, g*P); row 64 zeros (dummy)
    __shared__ int    pk[SW][16 + 256 + 64];  // packed tokens; P=pk+16; front pad=dummy
    __shared__ float  ldsbc[64];

    const int tid  = threadIdx.x;
    const int wave = tid >> 6;
    const int lane = tid & 63;

    {
        const float4* srcGc = (const float4*)(ws + OFF_GC);
        const float4* srcP  = (const float4*)(ws + OFF_P);
        for (int i = tid; i < 1024; i += SW * 64) {
            const float4 g4 = srcGc[i];
            const float4 p4 = srcP[i];
            const int base = i << 2;          // float2 index (same row-major layout)
            ldsGP[base + 0] = make_float2(g4.x, p4.x);
            ldsGP[base + 1] = make_float2(g4.y, p4.y);
            ldsGP[base + 2] = make_float2(g4.z, p4.z);
            ldsGP[base + 3] = make_float2(g4.w, p4.w);
        }
    }
    if (tid < 64) {
        ldsGP[4096 + tid] = make_float2(0.0f, 0.0f);   // dummy token 64 row
        ldsbc[tid] = ws[OFF_BC + tid];
    }
    const int b = blockIdx.x * SW + wave;
    int* P = pk[wave] + 16;
    {
        const int4* src = (const int4*)(seq + (size_t)b * Lsz);
        #pragma unroll
        for (int i = 0; i < 4; ++i) {
            const int4 tv = src[i * 64 + lane];
            P[i * 64 + lane] = tv.x | (tv.y << 8) | (tv.z << 16) | (tv.w << 24);
        }
        if (lane < 16) pk[wave][lane] = 0x40404040;   // front pad: token 64 (dummy)
    }
    __syncthreads();

    // last word holds steps 1020..1023; step 1023 is the query -> replace with dummy 64
    const int lastw = P[255];
    const int tokL  = (lastw >> 24) & 0xFF;
    if (lane == 0) P[255] = (lastw & 0x00FFFFFF) | (64 << 24);

    float D   = ws[OFF_G + (tokL << 6) + lane];   // D_v = h_v . q  (true Gram, L2-hot)
    float acc = ldsbc[lane];                      // logits accumulator

    int    tkA[16], tkB[16];
    float2 gpA[16], gpB[16];

    // prologue: block 0 words (steps 1023..992); group 0 (A, lanes 7..4),
    // group 1 (B, lanes 3..0)
    int tokv = P[248 + lane];
    #pragma unroll
    for (int j = 0; j < 4; ++j) {
        const int w = __builtin_amdgcn_readlane(tokv, 7 - j);
        tkA[4 * j + 0] = (w >> 24) & 0xFF;
        tkA[4 * j + 1] = (w >> 16) & 0xFF;
        tkA[4 * j + 2] = (w >>  8) & 0xFF;
        tkA[4 * j + 3] =  w        & 0xFF;
    }
    #pragma unroll
    for (int k = 0; k < 16; ++k) gpA[k] = ldsGP[(tkA[k] << 6) + lane];
    #pragma unroll
    for (int j = 0; j < 4; ++j) {
        const int w = __builtin_amdgcn_readlane(tokv, 3 - j);
        tkB[4 * j + 0] = (w >> 24) & 0xFF;
        tkB[4 * j + 1] = (w >> 16) & 0xFF;
        tkB[4 * j + 2] = (w >>  8) & 0xFF;
        tkB[4 * j + 3] =  w        & 0xFF;
    }
    #pragma unroll
    for (int k = 0; k < 16; ++k) gpB[k] = ldsGP[(tkB[k] << 6) + lane];

    // iteration n computes groups 2n (A), 2n+1 (B); gathers 2n+2, 2n+3 from
    // block n+1 words. n=31 gathers from the front pad (dummy) harmlessly.
    for (int n = 0; n < 32; ++n) {
        const int tokvN = P[240 - 8 * n + lane];   // block n+1 (n=31 -> pad)
        // compute A: group 2n  (chain: readlane -> fma(D); acc chain independent)
        __builtin_amdgcn_s_setprio(1);
        #pragma unroll
        for (int k = 0; k < 16; ++k) {
            const float d = __rlf(D, tkA[k]);
            D   = fmaf(-d, gpA[k].x, D);
            acc = fmaf( d, gpA[k].y, acc);
        }
        __builtin_amdgcn_s_setprio(0);
        // refill A: group 2n+2 tokens (tokvN lanes 7..4) + gather
        #pragma unroll
        for (int j = 0; j < 4; ++j) {
            const int w = __builtin_amdgcn_readlane(tokvN, 7 - j);
            tkA[4 * j + 0] = (w >> 24) & 0xFF;
            tkA[4 * j + 1] = (w >> 16) & 0xFF;
            tkA[4 * j + 2] = (w >>  8) & 0xFF;
            tkA[4 * j + 3] =  w        & 0xFF;
        }
        #pragma unroll
        for (int k = 0; k < 16; ++k) gpA[k] = ldsGP[(tkA[k] << 6) + lane];
        // compute B: group 2n+1
        __builtin_amdgcn_s_setprio(1);
        #pragma unroll
        for (int k = 0; k < 16; ++k) {
            const float d = __rlf(D, tkB[k]);
            D   = fmaf(-d, gpB[k].x, D);
            acc = fmaf( d, gpB[k].y, acc);
        }
        __builtin_amdgcn_s_setprio(0);
        // refill B: group 2n+3 tokens (tokvN lanes 3..0) + gather
        #pragma unroll
        for (int j = 0; j < 4; ++j) {
            const int w = __builtin_amdgcn_readlane(tokvN, 3 - j);
            tkB[4 * j + 0] = (w >> 24) & 0xFF;
            tkB[4 * j + 1] = (w >> 16) & 0xFF;
            tkB[4 * j + 2] = (w >>  8) & 0xFF;
            tkB[4 * j + 3] =  w        & 0xFF;
        }
        #pragma unroll
        for (int k = 0; k < 16; ++k) gpB[k] = ldsGP[(tkB[k] << 6) + lane];
    }

    out[(size_t)b * 64 + lane] = acc;
}

extern "C" void kernel_launch(void* const* d_in, const int* in_sizes, int n_in,
                              void* d_out, int out_size, void* d_ws, size_t ws_size,
                              hipStream_t stream) {
    const int*   seq     = (const int*)  d_in[0];
    const float* embed_W = (const float*)d_in[1];
    const float* ff_w1   = (const float*)d_in[2];
    const float* ff_b1   = (const float*)d_in[3];
    const float* ff_w2   = (const float*)d_in[4];
    const float* ff_b2   = (const float*)d_in[5];
    const float* ln_g    = (const float*)d_in[6];
    const float* ln_b    = (const float*)d_in[7];
    const float* gate_w1 = (const float*)d_in[8];
    const float* gate_b1 = (const float*)d_in[9];
    const float* gate_w2 = (const float*)d_in[10];
    const float* gate_b2 = (const float*)d_in[11];
    const float* read_w  = (const float*)d_in[12];
    const float* read_b  = (const float*)d_in[13];
    const float* out_w   = (const float*)d_in[14];
    const float* out_b   = (const float*)d_in[15];
    float* ws  = (float*)d_ws;
    float* out = (float*)d_out;

    hipLaunchKernelGGL(prep1_kernel, dim3(129), dim3(128), 0, stream,
                       embed_W, ff_w1, ff_b1, ff_w2, ff_b2, ln_g, ln_b,
                       gate_w1, gate_b1, gate_w2, gate_b2, read_w, read_b,
                       out_w, out_b, ws);
    hipLaunchKernelGGL(prep2_kernel, dim3(128), dim3(64), 0, stream, ws);
    hipLaunchKernelGGL(scan_kernel, dim3(Bsz / SW), dim3(SW * 64), 0, stream,
                       seq, ws, out);
}